// Round 6
// baseline (466.682 us; speedup 1.0000x reference)
//
#include <hip/hip_runtime.h>
#include <hip/hip_bf16.h>

// Sizes fixed by the reference
#define HV   128
#define HT   17
#define DIMD 290        // 2*(HV+HT)
#define KP   320        // K padded to 10*32 for mfma 16x16x32
#define OO   640        // 5*HV
#define RT   32         // rows per tile
#define KN   8          // number of types

typedef unsigned short u16;
typedef __attribute__((ext_vector_type(8))) short short8v;
typedef __attribute__((ext_vector_type(4))) float f32x4;

__device__ __forceinline__ u16 f2bf(float x) {
    unsigned u = __float_as_uint(x);
    u = (u + 0x7FFFu + ((u >> 16) & 1u)) >> 16;   // RNE
    return (u16)u;
}
__device__ __forceinline__ float sigf(float x) {
    return __builtin_amdgcn_rcpf(1.0f + __expf(-x));
}
__device__ __forceinline__ float tanhfast(float x) {
    return 1.0f - 2.0f * __builtin_amdgcn_rcpf(1.0f + __expf(2.0f * x));
}
__device__ __forceinline__ void gld16(const void* g, void* l) {
    __builtin_amdgcn_global_load_lds(
        (const __attribute__((address_space(1))) unsigned int*)g,
        (__attribute__((address_space(3))) unsigned int*)l, 16, 0, 0);
}

// ws header layout (ints): [0..7] counts, [8..15] scatter cursors,
// [16..24] blkStart prefix (blkStart[8] = total row-tiles)

__global__ void hist_k(const int* __restrict__ pt, int* __restrict__ hdr, int N) {
    __shared__ int c[KN];
    if (threadIdx.x < KN) c[threadIdx.x] = 0;
    __syncthreads();
    int n = blockIdx.x * 256 + threadIdx.x;
    if (n < N) atomicAdd(&c[pt[n]], 1);
    __syncthreads();
    if (threadIdx.x < KN && c[threadIdx.x]) atomicAdd(&hdr[threadIdx.x], c[threadIdx.x]);
}

__global__ void prefix_k(int* __restrict__ hdr) {
    if (threadIdx.x == 0 && blockIdx.x == 0) {
        int acc = 0;
        hdr[16] = 0;
        for (int k = 0; k < KN; ++k) {
            acc += (hdr[k] + RT - 1) / RT;
            hdr[17 + k] = acc;
        }
    }
}

__global__ void scatter_k(const int* __restrict__ pt, int* __restrict__ hdr,
                          int* __restrict__ idxbuf, int N) {
    __shared__ int c[KN], base[KN];
    if (threadIdx.x < KN) c[threadIdx.x] = 0;
    __syncthreads();
    int n = blockIdx.x * 256 + threadIdx.x;
    int k = 0, my = 0;
    if (n < N) { k = pt[n]; my = atomicAdd(&c[k], 1); }
    __syncthreads();
    if (threadIdx.x < KN)
        base[threadIdx.x] = c[threadIdx.x] ? atomicAdd(&hdr[8 + threadIdx.x], c[threadIdx.x]) : 0;
    __syncthreads();
    if (n < N) idxbuf[hdr[16 + k] * RT + base[k] + my] = n;
}

// W (K,O,290) fp32 -> Wbf (K,O,320) bf16 with column permutation:
// x' layout = [h_l 0..128 | h_r 128..256 | t_l 256..273 | t_r 273..290 | 0 pad]
__global__ void wconv_k(const float* __restrict__ W, u16* __restrict__ Wbf) {
    int k = blockIdx.y;
    int idx = blockIdx.x * 256 + threadIdx.x;
    if (idx >= OO * KP) return;
    int o = idx / KP, d = idx % KP;
    int src;
    if (d < 256)      src = (d < 128) ? d : d + 17;
    else if (d < 273) src = d - 128;
    else if (d < 290) src = d;
    else              src = -1;
    float v = (src >= 0) ? W[((size_t)k * OO + o) * DIMD + src] : 0.0f;
    Wbf[((size_t)k * OO + o) * KP + d] = f2bf(v);
}

// Build dense bf16 X (sorted rows, 320 cols, XOR-swizzled within each row)
// and meta[row] = (node, li, ri, 0). 8 threads per row, streaming, no barriers.
__global__ void __launch_bounds__(512)
buildx_k(const float* __restrict__ h_pool, const float* __restrict__ t_pool,
         const int* __restrict__ child_idx, const int* __restrict__ idxbuf,
         u16* __restrict__ X, int4* __restrict__ meta, int totrows) {
    int row = blockIdx.x * 64 + (threadIdx.x >> 3);
    int q = threadIdx.x & 7;
    if (row >= totrows) return;
    int node = idxbuf[row];
    char* xr = (char*)(X + (size_t)row * KP);
    const int swz = (row & 7) << 4;           // byte-XOR within the row

    if (node >= 0) {
        int li = child_idx[2 * node], ri = child_idx[2 * node + 1];
        if (q == 0) meta[row] = make_int4(node, li, ri, 0);
        const float4* hl = (const float4*)(h_pool + (size_t)li * HV);
        const float4* hr = (const float4*)(h_pool + (size_t)ri * HV);
        #pragma unroll
        for (int m = 0; m < 4; ++m) {
            float4 v = hl[q + 8 * m];
            *(ushort4*)(xr + (((q + 8 * m) * 8) ^ swz)) =
                make_ushort4(f2bf(v.x), f2bf(v.y), f2bf(v.z), f2bf(v.w));
        }
        #pragma unroll
        for (int m = 0; m < 4; ++m) {
            float4 v = hr[q + 8 * m];
            *(ushort4*)(xr + ((256 + (q + 8 * m) * 8) ^ swz)) =
                make_ushort4(f2bf(v.x), f2bf(v.y), f2bf(v.z), f2bf(v.w));
        }
        const float* tl = t_pool + (size_t)li * HT;
        const float* tr = t_pool + (size_t)ri * HT;
        *(u16*)(xr + ((512 + 2 * q) ^ swz))       = f2bf(tl[q]);
        *(u16*)(xr + ((512 + 2 * (q + 8)) ^ swz)) = f2bf(tl[q + 8]);
        *(u16*)(xr + ((546 + 2 * q) ^ swz))       = f2bf(tr[q]);
        *(u16*)(xr + ((546 + 2 * (q + 8)) ^ swz)) = f2bf(tr[q + 8]);
        if (q == 0) {
            *(u16*)(xr + (544 ^ swz)) = f2bf(tl[16]);
            *(u16*)(xr + (578 ^ swz)) = f2bf(tr[16]);
        }
        for (int b = 580 + 2 * q; b < 640; b += 16)
            *(u16*)(xr + (b ^ swz)) = 0;
    } else {
        if (q == 0) meta[row] = make_int4(-1, 0, 0, 0);
        ushort4 z = make_ushort4(0, 0, 0, 0);
        for (int b = q * 8; b < 640; b += 64)
            *(ushort4*)(xr + (b ^ swz)) = z;
    }
}

// Dense GEMM + fused LSTM. One block per 32-row tile, 8 waves, wave = 32r x 16
// h-cols x 5 gates. X staged via global_load_lds; meta/c_pool/bias prefetched
// from global BEFORE the barrier (overlaps X staging latency).
__global__ __launch_bounds__(512, 4)
void gemm_lstm_k(const float* __restrict__ c_pool, const float* __restrict__ bias,
                 const u16* __restrict__ Wbf, const u16* __restrict__ X,
                 const int4* __restrict__ meta, const int* __restrict__ hdr,
                 float* __restrict__ out) {
    __shared__ u16 sX[RT * KP];          // 20480 B, linear (swizzle pre-baked)

    const int bx  = blockIdx.x;
    const int tid = threadIdx.x;

    // ---- stage X tile: 20KB via global_load_lds (16B/lane) ----
    {
        const char* src = (const char*)X + (size_t)bx * (RT * KP * 2) + tid * 16;
        char* dst = (char*)sX + tid * 16;
        gld16(src, dst);
        gld16(src + 8192, dst + 8192);
        if (tid < 256) gld16(src + 16384, dst + 16384);
    }

    const int wc = tid >> 6, lane = tid & 63;
    const int lo = lane & 15, hi = lane >> 4;
    const int hcol = wc * 16 + lo;

    // ---- pre-barrier prefetch: type, meta, c_pool, bias (LDS-independent) ----
    int k = 0;
    #pragma unroll
    for (int j = 0; j < 7; ++j) k += (bx >= hdr[17 + j]);

    int nodes[8];
    float cpl[8], cpr[8];
    #pragma unroll
    for (int m = 0; m < 2; ++m)
        #pragma unroll
        for (int jj = 0; jj < 4; ++jj) {
            int4 mt = meta[(size_t)bx * RT + m * 16 + hi * 4 + jj];
            nodes[m * 4 + jj] = mt.x;
            cpl[m * 4 + jj] = c_pool[(size_t)mt.y * HV + hcol];
            cpr[m * 4 + jj] = c_pool[(size_t)mt.z * HV + hcol];
        }
    float bb[5];
    #pragma unroll
    for (int g = 0; g < 5; ++g) bb[g] = bias[k * OO + g * 128 + hcol];

    __syncthreads();   // drains vmcnt (global_load_lds + prefetch) + lgkm

    // ---- MFMA main loop, 1-deep W prefetch ----
    f32x4 acc[5][2];
    #pragma unroll
    for (int g = 0; g < 5; ++g)
        #pragma unroll
        for (int m = 0; m < 2; ++m)
            acc[g][m] = (f32x4){0.f, 0.f, 0.f, 0.f};

    const u16* __restrict__ wbase = Wbf + (size_t)k * (OO * KP);
    int wo[5];
    #pragma unroll
    for (int g = 0; g < 5; ++g)
        wo[g] = (g * 128 + wc * 16 + lo) * KP + hi * 8;

    const char* sXb = (const char*)sX;
    const int rowbase = lo * 640;             // byte offset of row lo
    const int swzl = (lo & 7) << 4;           // same XOR the writer used

    short8v bcur = *(const short8v*)(wbase + wo[0]);   // kk=0, g=0
    #pragma unroll
    for (int kk = 0; kk < 10; ++kk) {
        const int kb = kk * 32;
        int a_off = rowbase + ((kk * 64 + hi * 16) ^ swzl);
        short8v a0 = *(const short8v*)(sXb + a_off);
        short8v a1 = *(const short8v*)(sXb + a_off + 10240);
        #pragma unroll
        for (int g = 0; g < 5; ++g) {
            short8v bnext;
            if (g < 4)       bnext = *(const short8v*)(wbase + wo[g + 1] + kb);
            else if (kk < 9) bnext = *(const short8v*)(wbase + wo[0] + kb + 32);
            acc[g][0] = __builtin_amdgcn_mfma_f32_16x16x32_bf16(a0, bcur, acc[g][0], 0, 0, 0);
            acc[g][1] = __builtin_amdgcn_mfma_f32_16x16x32_bf16(a1, bcur, acc[g][1], 0, 0, 0);
            if (g < 4 || kk < 9) bcur = bnext;
        }
    }

    // ---- fused LSTM epilogue ----
    #pragma unroll
    for (int m = 0; m < 2; ++m) {
        #pragma unroll
        for (int jj = 0; jj < 4; ++jj) {
            int node = nodes[m * 4 + jj];
            if (node < 0) continue;
            float cl = cpl[m * 4 + jj], cr = cpr[m * 4 + jj];
            float gi  = acc[0][m][jj] + bb[0];
            float gfl = acc[1][m][jj] + bb[1];
            float gfr = acc[2][m][jj] + bb[2];
            float gu  = acc[3][m][jj] + bb[3];
            float go  = acc[4][m][jj] + bb[4];
            float cc = sigf(gi) * tanhfast(gu) + sigf(gfl) * cl + sigf(gfr) * cr;
            float hh = sigf(go) * tanhfast(cc);
            float* orow = out + (size_t)node * (2 * HV);
            orow[hcol]      = hh;
            orow[HV + hcol] = cc;
        }
    }
}

extern "C" void kernel_launch(void* const* d_in, const int* in_sizes, int n_in,
                              void* d_out, int out_size, void* d_ws, size_t ws_size,
                              hipStream_t stream) {
    const float* h_pool      = (const float*)d_in[0];
    const float* c_pool      = (const float*)d_in[1];
    const float* t_pool      = (const float*)d_in[2];
    const int*   child_idx   = (const int*)d_in[3];
    const int*   parent_type = (const int*)d_in[4];
    const float* W           = (const float*)d_in[5];
    const float* bias        = (const float*)d_in[6];
    float* out = (float*)d_out;

    const int N = in_sizes[3] / 2;
    const int maxblk = (N + RT - 1) / RT + KN;    // upper bound on row-tiles
    const int totrows = maxblk * RT;

    char* ws = (char*)d_ws;
    size_t off = 0;
    int* hdr = (int*)ws;                         off += 1024;
    int* idxbuf = (int*)(ws + off);              off += (((size_t)totrows * 4 + 255) / 256) * 256;
    int4* meta = (int4*)(ws + off);              off += (size_t)totrows * 16;
    u16* Wbf = (u16*)(ws + off);                 off += (size_t)KN * OO * KP * 2;
    u16* X = (u16*)(ws + off);                   off += (size_t)totrows * KP * 2;

    hipMemsetAsync(hdr, 0, 1024, stream);
    hipMemsetAsync(idxbuf, 0xFF, (size_t)totrows * 4, stream);

    int nb = (N + 255) / 256;
    hist_k<<<nb, 256, 0, stream>>>(parent_type, hdr, N);
    prefix_k<<<1, 64, 0, stream>>>(hdr);
    scatter_k<<<nb, 256, 0, stream>>>(parent_type, hdr, idxbuf, N);
    wconv_k<<<dim3((OO * KP + 255) / 256, KN), 256, 0, stream>>>(W, Wbf);
    buildx_k<<<(totrows + 63) / 64, 512, 0, stream>>>(h_pool, t_pool, child_idx, idxbuf, X, meta, totrows);
    gemm_lstm_k<<<maxblk, 512, 0, stream>>>(c_pool, bias, Wbf, X, meta, hdr, out);
}

// Round 7
// 359.890 us; speedup vs baseline: 1.2967x; 1.2967x over previous
//
#include <hip/hip_runtime.h>
#include <hip/hip_bf16.h>

// Sizes fixed by the reference
#define HV   128
#define HT   17
#define DIMD 290        // 2*(HV+HT)
#define KP   320        // K padded to 10*32 for mfma 16x16x32
#define OO   640        // 5*HV
#define RT   64         // rows per tile
#define KN   8          // number of types

typedef unsigned short u16;
typedef __attribute__((ext_vector_type(8))) short short8v;
typedef __attribute__((ext_vector_type(4))) float f32x4;

__device__ __forceinline__ u16 f2bf(float x) {
    unsigned u = __float_as_uint(x);
    u = (u + 0x7FFFu + ((u >> 16) & 1u)) >> 16;   // RNE
    return (u16)u;
}
__device__ __forceinline__ float sigf(float x) {
    return __builtin_amdgcn_rcpf(1.0f + __expf(-x));
}
__device__ __forceinline__ float tanhfast(float x) {
    return 1.0f - 2.0f * __builtin_amdgcn_rcpf(1.0f + __expf(2.0f * x));
}
__device__ __forceinline__ void gld16(const void* g, void* l) {
    __builtin_amdgcn_global_load_lds(
        (const __attribute__((address_space(1))) unsigned int*)g,
        (__attribute__((address_space(3))) unsigned int*)l, 16, 0, 0);
}

// ws header layout (ints): [0..7] counts, [8..15] scatter cursors,
// [16..24] blkStart prefix (blkStart[8] = total row-tiles)

__global__ void hist_k(const int* __restrict__ pt, int* __restrict__ hdr, int N) {
    __shared__ int c[KN];
    if (threadIdx.x < KN) c[threadIdx.x] = 0;
    __syncthreads();
    int n = blockIdx.x * 256 + threadIdx.x;
    if (n < N) atomicAdd(&c[pt[n]], 1);
    __syncthreads();
    if (threadIdx.x < KN && c[threadIdx.x]) atomicAdd(&hdr[threadIdx.x], c[threadIdx.x]);
}

__global__ void prefix_k(int* __restrict__ hdr) {
    if (threadIdx.x == 0 && blockIdx.x == 0) {
        int acc = 0;
        hdr[16] = 0;
        for (int k = 0; k < KN; ++k) {
            acc += (hdr[k] + RT - 1) / RT;
            hdr[17 + k] = acc;
        }
    }
}

__global__ void scatter_k(const int* __restrict__ pt, int* __restrict__ hdr,
                          int* __restrict__ idxbuf, int N) {
    __shared__ int c[KN], base[KN];
    if (threadIdx.x < KN) c[threadIdx.x] = 0;
    __syncthreads();
    int n = blockIdx.x * 256 + threadIdx.x;
    int k = 0, my = 0;
    if (n < N) { k = pt[n]; my = atomicAdd(&c[k], 1); }
    __syncthreads();
    if (threadIdx.x < KN)
        base[threadIdx.x] = c[threadIdx.x] ? atomicAdd(&hdr[8 + threadIdx.x], c[threadIdx.x]) : 0;
    __syncthreads();
    if (n < N) idxbuf[hdr[16 + k] * RT + base[k] + my] = n;
}

// W (K,O,290) fp32 -> Wt (K, 10, 640, 32) bf16, K-major-tiled + column perm.
// x' layout = [h_l 0..128 | h_r 128..256 | t_l 256..273 | t_r 273..290 | 0 pad]
// Wt[((k*10 + kk)*640 + o)*32 + e] = W[k][o][perm(kk*32+e)]
// -> a wave's B-fragment load (16 cols x 8 K-elems, 16B/lane) is 1KB contiguous.
__global__ void wconv_k(const float* __restrict__ W, u16* __restrict__ Wt) {
    int k = blockIdx.y;
    int idx = blockIdx.x * 256 + threadIdx.x;
    if (idx >= OO * KP) return;
    int o = idx / KP, d = idx % KP;
    int src;
    if (d < 256)      src = (d < 128) ? d : d + 17;
    else if (d < 273) src = d - 128;
    else if (d < 290) src = d;
    else              src = -1;
    float v = (src >= 0) ? W[((size_t)k * OO + o) * DIMD + src] : 0.0f;
    int kk = d >> 5, e = d & 31;
    Wt[(((size_t)k * 10 + kk) * OO + o) * 32 + e] = f2bf(v);
}

// Build dense bf16 X (sorted rows, 320 cols, XOR-swizzled within each row)
// and meta[row] = (node, li, ri, 0). 8 threads per row, streaming, no barriers.
__global__ void __launch_bounds__(512)
buildx_k(const float* __restrict__ h_pool, const float* __restrict__ t_pool,
         const int* __restrict__ child_idx, const int* __restrict__ idxbuf,
         u16* __restrict__ X, int4* __restrict__ meta, int totrows) {
    int row = blockIdx.x * 64 + (threadIdx.x >> 3);
    int q = threadIdx.x & 7;
    if (row >= totrows) return;
    int node = idxbuf[row];
    char* xr = (char*)(X + (size_t)row * KP);
    const int swz = (row & 7) << 4;           // byte-XOR within the row

    if (node >= 0) {
        int li = child_idx[2 * node], ri = child_idx[2 * node + 1];
        if (q == 0) meta[row] = make_int4(node, li, ri, 0);
        const float4* hl = (const float4*)(h_pool + (size_t)li * HV);
        const float4* hr = (const float4*)(h_pool + (size_t)ri * HV);
        #pragma unroll
        for (int m = 0; m < 4; ++m) {
            float4 v = hl[q + 8 * m];
            *(ushort4*)(xr + (((q + 8 * m) * 8) ^ swz)) =
                make_ushort4(f2bf(v.x), f2bf(v.y), f2bf(v.z), f2bf(v.w));
        }
        #pragma unroll
        for (int m = 0; m < 4; ++m) {
            float4 v = hr[q + 8 * m];
            *(ushort4*)(xr + ((256 + (q + 8 * m) * 8) ^ swz)) =
                make_ushort4(f2bf(v.x), f2bf(v.y), f2bf(v.z), f2bf(v.w));
        }
        const float* tl = t_pool + (size_t)li * HT;
        const float* tr = t_pool + (size_t)ri * HT;
        *(u16*)(xr + ((512 + 2 * q) ^ swz))       = f2bf(tl[q]);
        *(u16*)(xr + ((512 + 2 * (q + 8)) ^ swz)) = f2bf(tl[q + 8]);
        *(u16*)(xr + ((546 + 2 * q) ^ swz))       = f2bf(tr[q]);
        *(u16*)(xr + ((546 + 2 * (q + 8)) ^ swz)) = f2bf(tr[q + 8]);
        if (q == 0) {
            *(u16*)(xr + (544 ^ swz)) = f2bf(tl[16]);
            *(u16*)(xr + (578 ^ swz)) = f2bf(tr[16]);
        }
        for (int b = 580 + 2 * q; b < 640; b += 16)
            *(u16*)(xr + (b ^ swz)) = 0;
    } else {
        if (q == 0) meta[row] = make_int4(-1, 0, 0, 0);
        ushort4 z = make_ushort4(0, 0, 0, 0);
        for (int b = q * 8; b < 640; b += 64)
            *(ushort4*)(xr + (b ^ swz)) = z;
    }
}

// Dense GEMM + fused LSTM. One block per 64-row tile, 8 waves, wave = 64r x 16
// h-cols x 5 gates. X via global_load_lds (swizzle pre-baked); W via coalesced
// Wt fragments with explicit 1-kk-lookahead double buffering (W and A frags);
// meta/c_pool/bias prefetched from global BEFORE the barrier.
__global__ __launch_bounds__(512, 2)
void gemm_lstm_k(const float* __restrict__ c_pool, const float* __restrict__ bias,
                 const u16* __restrict__ Wt, const u16* __restrict__ X,
                 const int4* __restrict__ meta, const int* __restrict__ hdr,
                 float* __restrict__ out) {
    __shared__ u16 sX[RT * KP];          // 40960 B, linear (swizzle pre-baked)

    const int bx  = blockIdx.x;
    const int tid = threadIdx.x;

    // ---- stage X tile: 40KB via global_load_lds (16B/lane x 5) ----
    {
        const char* src = (const char*)X + (size_t)bx * (RT * KP * 2) + tid * 16;
        char* dst = (char*)sX + tid * 16;
        #pragma unroll
        for (int i = 0; i < 5; ++i)
            gld16(src + i * 8192, dst + i * 8192);
    }

    const int wc = tid >> 6, lane = tid & 63;
    const int lo = lane & 15, hi = lane >> 4;
    const int hcol = wc * 16 + lo;

    // ---- pre-barrier prefetch: type, meta, c_pool, bias (LDS-independent) ----
    int k = 0;
    #pragma unroll
    for (int j = 0; j < 7; ++j) k += (bx >= hdr[17 + j]);

    int nodes[16];
    float cpl[16], cpr[16];
    #pragma unroll
    for (int m = 0; m < 4; ++m)
        #pragma unroll
        for (int jj = 0; jj < 4; ++jj) {
            int4 mt = meta[(size_t)bx * RT + m * 16 + hi * 4 + jj];
            nodes[m * 4 + jj] = mt.x;
            cpl[m * 4 + jj] = c_pool[(size_t)mt.y * HV + hcol];
            cpr[m * 4 + jj] = c_pool[(size_t)mt.z * HV + hcol];
        }
    float bb[5];
    #pragma unroll
    for (int g = 0; g < 5; ++g) bb[g] = bias[k * OO + g * 128 + hcol];

    __syncthreads();   // drains vmcnt (global_load_lds + prefetch) + lgkm

    // ---- MFMA main loop: 1-kk lookahead on both W (L2) and A (LDS) ----
    f32x4 acc[5][4];
    #pragma unroll
    for (int g = 0; g < 5; ++g)
        #pragma unroll
        for (int m = 0; m < 4; ++m)
            acc[g][m] = (f32x4){0.f, 0.f, 0.f, 0.f};

    // Wt fragment base: ((k*10 + kk)*640 + g*128 + hcol)*32 + hi*8
    const u16* __restrict__ wt = Wt + ((size_t)k * 10 * OO) * 32;
    int wo[5];
    #pragma unroll
    for (int g = 0; g < 5; ++g)
        wo[g] = (g * 128 + hcol) * 32 + hi * 8;

    const char* sXb = (const char*)sX;
    const int rowbase = lo * 640;             // byte offset of row lo
    const int swzl = (lo & 7) << 4;           // same XOR the writer used

    short8v wfa[5], wfb[5];
    short8v aa[4], ab[4];

    #pragma unroll
    for (int g = 0; g < 5; ++g) wfa[g] = *(const short8v*)(wt + wo[g]);
    {
        int a_off = rowbase + ((hi * 16) ^ swzl);
        #pragma unroll
        for (int m = 0; m < 4; ++m)
            aa[m] = *(const short8v*)(sXb + a_off + m * 10240);
    }

    #pragma unroll
    for (int kk = 0; kk < 10; ++kk) {
        short8v (&wcur)[5] = (kk & 1) ? wfb : wfa;
        short8v (&wnxt)[5] = (kk & 1) ? wfa : wfb;
        short8v (&acur)[4] = (kk & 1) ? ab : aa;
        short8v (&anxt)[4] = (kk & 1) ? aa : ab;
        if (kk < 9) {
            const u16* wtn = wt + (size_t)(kk + 1) * (OO * 32);
            #pragma unroll
            for (int g = 0; g < 5; ++g)
                wnxt[g] = *(const short8v*)(wtn + wo[g]);
            int a_off = rowbase + (((kk + 1) * 64 + hi * 16) ^ swzl);
            #pragma unroll
            for (int m = 0; m < 4; ++m)
                anxt[m] = *(const short8v*)(sXb + a_off + m * 10240);
        }
        #pragma unroll
        for (int g = 0; g < 5; ++g) {
            acc[g][0] = __builtin_amdgcn_mfma_f32_16x16x32_bf16(acur[0], wcur[g], acc[g][0], 0, 0, 0);
            acc[g][1] = __builtin_amdgcn_mfma_f32_16x16x32_bf16(acur[1], wcur[g], acc[g][1], 0, 0, 0);
            acc[g][2] = __builtin_amdgcn_mfma_f32_16x16x32_bf16(acur[2], wcur[g], acc[g][2], 0, 0, 0);
            acc[g][3] = __builtin_amdgcn_mfma_f32_16x16x32_bf16(acur[3], wcur[g], acc[g][3], 0, 0, 0);
        }
    }

    // ---- fused LSTM epilogue ----
    #pragma unroll
    for (int m = 0; m < 4; ++m) {
        #pragma unroll
        for (int jj = 0; jj < 4; ++jj) {
            int node = nodes[m * 4 + jj];
            if (node < 0) continue;
            float cl = cpl[m * 4 + jj], cr = cpr[m * 4 + jj];
            float gi  = acc[0][m][jj] + bb[0];
            float gfl = acc[1][m][jj] + bb[1];
            float gfr = acc[2][m][jj] + bb[2];
            float gu  = acc[3][m][jj] + bb[3];
            float go  = acc[4][m][jj] + bb[4];
            float cc = sigf(gi) * tanhfast(gu) + sigf(gfl) * cl + sigf(gfr) * cr;
            float hh = sigf(go) * tanhfast(cc);
            float* orow = out + (size_t)node * (2 * HV);
            orow[hcol]      = hh;
            orow[HV + hcol] = cc;
        }
    }
}

extern "C" void kernel_launch(void* const* d_in, const int* in_sizes, int n_in,
                              void* d_out, int out_size, void* d_ws, size_t ws_size,
                              hipStream_t stream) {
    const float* h_pool      = (const float*)d_in[0];
    const float* c_pool      = (const float*)d_in[1];
    const float* t_pool      = (const float*)d_in[2];
    const int*   child_idx   = (const int*)d_in[3];
    const int*   parent_type = (const int*)d_in[4];
    const float* W           = (const float*)d_in[5];
    const float* bias        = (const float*)d_in[6];
    float* out = (float*)d_out;

    const int N = in_sizes[3] / 2;
    const int maxblk = (N + RT - 1) / RT + KN;    // upper bound on row-tiles
    const int totrows = maxblk * RT;

    char* ws = (char*)d_ws;
    size_t off = 0;
    int* hdr = (int*)ws;                         off += 1024;
    int* idxbuf = (int*)(ws + off);              off += (((size_t)totrows * 4 + 255) / 256) * 256;
    int4* meta = (int4*)(ws + off);              off += (size_t)totrows * 16;
    u16* Wt = (u16*)(ws + off);                  off += (size_t)KN * OO * KP * 2;
    u16* X = (u16*)(ws + off);                   off += (size_t)totrows * KP * 2;

    hipMemsetAsync(hdr, 0, 1024, stream);
    hipMemsetAsync(idxbuf, 0xFF, (size_t)totrows * 4, stream);

    int nb = (N + 255) / 256;
    hist_k<<<nb, 256, 0, stream>>>(parent_type, hdr, N);
    prefix_k<<<1, 64, 0, stream>>>(hdr);
    scatter_k<<<nb, 256, 0, stream>>>(parent_type, hdr, idxbuf, N);
    wconv_k<<<dim3((OO * KP + 255) / 256, KN), 256, 0, stream>>>(W, Wt);
    buildx_k<<<(totrows + 63) / 64, 512, 0, stream>>>(h_pool, t_pool, child_idx, idxbuf, X, meta, totrows);
    gemm_lstm_k<<<maxblk, 512, 0, stream>>>(c_pool, bias, Wt, X, meta, hdr, out);
}